// Round 6
// baseline (3146.031 us; speedup 1.0000x reference)
//
#include <hip/hip_runtime.h>
#include <cstddef>

// ---------------------------------------------------------------------------
// RQ-VAE forward on MI355X. Round 6: register-blocked RVQ (T=2 tokens/lane,
// h-split kept). Convs unchanged from validated R5 set.
// ---------------------------------------------------------------------------

template<int ACT> __device__ __forceinline__ float actf(float v) {
    if constexpr (ACT == 1) return v > 0.f ? v : 0.f;            // relu
    else if constexpr (ACT == 2) return v > 0.f ? v : 0.01f * v; // leaky relu
    else return v;
}
__device__ __forceinline__ float lrelu_in(float v) { return v > 0.f ? v : 0.01f * v; }

// ---------------------------------------------------------------------------
// Direct conv: thread = NPY vertical output pixels x 16 output channels.
// (validated R3/R5)
// ---------------------------------------------------------------------------
template<int CIN, int COUT, int K, int S, int P, int HIN, int WIN, int HOUT, int WOUT,
         int ICC, int NPY, int ACT, bool BIAS>
__launch_bounds__(256, 4)
__global__ void conv_k(const float* __restrict__ in, const float* __restrict__ w,
                       const float* __restrict__ bias, float* __restrict__ out)
{
    constexpr int K2 = K * K;
    constexpr int NR = S * (NPY - 1) + K;
    constexpr int BH = 16 * NPY;
    __shared__ float sw[ICC * K2 * 16];
    const int tid = threadIdx.x;
    const int tx = tid & 15, ty = tid >> 4;
    constexpr int TW = WOUT / 16;
    const int bx = blockIdx.x % TW, by = blockIdx.x / TW;
    const int ox = bx * 16 + tx;
    const int oy0 = by * BH + ty * NPY;
    const int oc0 = blockIdx.y * 16;
    const int n = blockIdx.z;
    const int ix0 = ox * S - P, iy0 = oy0 * S - P;

    int ro[NR]; float mr[NR];
#pragma unroll
    for (int r = 0; r < NR; ++r) {
        const int iy = iy0 + r;
        const bool v = (iy >= 0) && (iy < HIN);
        ro[r] = v ? iy * WIN : 0;
        mr[r] = v ? 1.f : 0.f;
    }
    int co[K]; float mc[K];
#pragma unroll
    for (int c = 0; c < K; ++c) {
        const int ix = ix0 + c;
        const bool v = (ix >= 0) && (ix < WIN);
        co[c] = v ? ix : 0;
        mc[c] = v ? 1.f : 0.f;
    }

    float acc[NPY][16];
#pragma unroll
    for (int py = 0; py < NPY; ++py)
#pragma unroll
        for (int j = 0; j < 16; ++j) acc[py][j] = 0.f;

    for (int ic0 = 0; ic0 < CIN; ic0 += ICC) {
        __syncthreads();
        for (int t = tid; t < ICC * K2 * 16; t += 256) {
            int oc_l = t & 15, r = t >> 4, k = r % K2, ic_l = r / K2;
            sw[(ic_l * K2 + k) * 16 + oc_l] =
                w[((size_t)(oc0 + oc_l) * CIN + ic0 + ic_l) * K2 + k];
        }
        __syncthreads();
#pragma unroll 1
        for (int ic_l = 0; ic_l < ICC; ++ic_l) {
            const float* ip = in + (size_t)(n * CIN + ic0 + ic_l) * HIN * WIN;
            float patch[NR][K];
#pragma unroll
            for (int r = 0; r < NR; ++r)
#pragma unroll
                for (int c = 0; c < K; ++c)
                    patch[r][c] = ip[ro[r] + co[c]] * (mr[r] * mc[c]);
            const float* swp = &sw[ic_l * K2 * 16];
#pragma unroll
            for (int ky = 0; ky < K; ++ky) {
#pragma unroll
                for (int kx = 0; kx < K; ++kx) {
                    const float4* wp = (const float4*)&swp[(ky * K + kx) * 16];
                    float4 w0 = wp[0], w1 = wp[1], w2 = wp[2], w3 = wp[3];
#pragma unroll
                    for (int py = 0; py < NPY; ++py) {
                        const float v = patch[py * S + ky][kx];
                        acc[py][0]  = fmaf(w0.x, v, acc[py][0]);
                        acc[py][1]  = fmaf(w0.y, v, acc[py][1]);
                        acc[py][2]  = fmaf(w0.z, v, acc[py][2]);
                        acc[py][3]  = fmaf(w0.w, v, acc[py][3]);
                        acc[py][4]  = fmaf(w1.x, v, acc[py][4]);
                        acc[py][5]  = fmaf(w1.y, v, acc[py][5]);
                        acc[py][6]  = fmaf(w1.z, v, acc[py][6]);
                        acc[py][7]  = fmaf(w1.w, v, acc[py][7]);
                        acc[py][8]  = fmaf(w2.x, v, acc[py][8]);
                        acc[py][9]  = fmaf(w2.y, v, acc[py][9]);
                        acc[py][10] = fmaf(w2.z, v, acc[py][10]);
                        acc[py][11] = fmaf(w2.w, v, acc[py][11]);
                        acc[py][12] = fmaf(w3.x, v, acc[py][12]);
                        acc[py][13] = fmaf(w3.y, v, acc[py][13]);
                        acc[py][14] = fmaf(w3.z, v, acc[py][14]);
                        acc[py][15] = fmaf(w3.w, v, acc[py][15]);
                    }
                }
            }
        }
    }
#pragma unroll
    for (int py = 0; py < NPY; ++py) {
#pragma unroll
        for (int j = 0; j < 16; ++j) {
            float r = acc[py][j];
            if (BIAS) r += bias[oc0 + j];
            r = actf<ACT>(r);
            out[((size_t)(n * COUT + oc0 + j) * HOUT + oy0 + py) * WOUT + ox] = r;
        }
    }
}

// ---------------------------------------------------------------------------
// 1x1 conv over 64x64 maps (HW=4096), 2 pixels per thread. (validated R3/R5)
// ---------------------------------------------------------------------------
template<int CIN, int COUT, int ACT, bool BIAS, bool INL, bool RESID, bool TOK>
__launch_bounds__(256, 4)
__global__ void conv1x1_k(const float* __restrict__ in, const float* __restrict__ w,
                          const float* __restrict__ bias, const float* __restrict__ resid,
                          float* __restrict__ out)
{
    constexpr int HW = 4096;
    __shared__ float sw[16 * CIN];
    const int tid = threadIdx.x;
    const int p0 = blockIdx.x * 512 + tid;
    const int p1 = p0 + 256;
    const int oc0 = blockIdx.y * 16;
    const int n = blockIdx.z;

    for (int t = tid; t < 16 * CIN; t += 256) {
        int oc_l = t & 15, ic = t >> 4;
        sw[ic * 16 + oc_l] = w[(size_t)(oc0 + oc_l) * CIN + ic];
    }
    __syncthreads();

    float acc[2][16];
#pragma unroll
    for (int p = 0; p < 2; ++p)
#pragma unroll
        for (int j = 0; j < 16; ++j) acc[p][j] = 0.f;

    const float* ip = in + (size_t)n * CIN * HW;
#pragma unroll 2
    for (int ic = 0; ic < CIN; ++ic) {
        float v0 = ip[(size_t)ic * HW + p0];
        float v1 = ip[(size_t)ic * HW + p1];
        if (INL) { v0 = lrelu_in(v0); v1 = lrelu_in(v1); }
        const float4* wp = (const float4*)&sw[ic * 16];
#pragma unroll
        for (int q4 = 0; q4 < 4; ++q4) {
            float4 wv = wp[q4];
            acc[0][q4 * 4 + 0] = fmaf(wv.x, v0, acc[0][q4 * 4 + 0]);
            acc[0][q4 * 4 + 1] = fmaf(wv.y, v0, acc[0][q4 * 4 + 1]);
            acc[0][q4 * 4 + 2] = fmaf(wv.z, v0, acc[0][q4 * 4 + 2]);
            acc[0][q4 * 4 + 3] = fmaf(wv.w, v0, acc[0][q4 * 4 + 3]);
            acc[1][q4 * 4 + 0] = fmaf(wv.x, v1, acc[1][q4 * 4 + 0]);
            acc[1][q4 * 4 + 1] = fmaf(wv.y, v1, acc[1][q4 * 4 + 1]);
            acc[1][q4 * 4 + 2] = fmaf(wv.z, v1, acc[1][q4 * 4 + 2]);
            acc[1][q4 * 4 + 3] = fmaf(wv.w, v1, acc[1][q4 * 4 + 3]);
        }
    }
#pragma unroll
    for (int p = 0; p < 2; ++p) {
        const int pix = p == 0 ? p0 : p1;
#pragma unroll
        for (int j = 0; j < 16; ++j) {
            float r = acc[p][j];
            if (BIAS) r += bias[oc0 + j];
            r = actf<ACT>(r);
            if (RESID) r += resid[((size_t)(n * COUT + oc0 + j)) * HW + pix];
            if (TOK)
                out[((size_t)n * HW + pix) * COUT + oc0 + j] = r;
            else
                out[((size_t)(n * COUT + oc0 + j)) * HW + pix] = r;
        }
    }
}

// ---------------------------------------------------------------------------
// ConvTranspose2d k=4 s=2 p=1, parity decomposition. (validated R2/R5)
// ---------------------------------------------------------------------------
template<int CIN, int COUT, int OCT, int HIN, int ICC, int ACT, bool INL>
__launch_bounds__(256, 3)
__global__ void convt_k(const float* __restrict__ in, const float* __restrict__ w,
                        const float* __restrict__ bias, float* __restrict__ out)
{
    constexpr int WIN = HIN, HOUT = 2 * HIN, WOUT = 2 * HIN;
    __shared__ float sw[ICC * 16 * OCT];
    const int tid = threadIdx.x;
    const int tx = tid & 15, ty = tid >> 4;
    constexpr int TBW = WOUT / 32;
    const int bx = blockIdx.x % TBW, by = blockIdx.x / TBW;
    const int A = by * 16 + ty;
    const int C = bx * 16 + tx;
    const int oc0 = blockIdx.y * OCT;
    const int n = blockIdx.z;

    int offs[9]; float msk[9];
#pragma unroll
    for (int dy = 0; dy < 3; ++dy) {
#pragma unroll
        for (int dx = 0; dx < 3; ++dx) {
            const int iy = A - 1 + dy, ix = C - 1 + dx;
            const bool v = (iy >= 0) && (iy < HIN) && (ix >= 0) && (ix < WIN);
            offs[dy * 3 + dx] = v ? iy * WIN + ix : 0;
            msk[dy * 3 + dx] = v ? 1.f : 0.f;
        }
    }

    float acc[4 * OCT];
#pragma unroll
    for (int j = 0; j < 4 * OCT; ++j) acc[j] = 0.f;

    for (int ic0 = 0; ic0 < CIN; ic0 += ICC) {
        __syncthreads();
        for (int t = tid; t < ICC * 16 * OCT; t += 256) {
            int oc_l = t % OCT, r = t / OCT, k = r & 15, ic_l = r >> 4;
            sw[(ic_l * 16 + k) * OCT + oc_l] =
                w[((size_t)(ic0 + ic_l) * COUT + oc0 + oc_l) * 16 + k];
        }
        __syncthreads();
#pragma unroll 1
        for (int ic_l = 0; ic_l < ICC; ++ic_l) {
            const float* ip = in + (size_t)(n * CIN + ic0 + ic_l) * HIN * WIN;
            float in9[9];
#pragma unroll
            for (int j = 0; j < 9; ++j) {
                float v = ip[offs[j]] * msk[j];
                if (INL) v = lrelu_in(v);
                in9[j] = v;
            }
#pragma unroll
            for (int ky = 0; ky < 4; ++ky) {
                const int ry = (ky + 1) & 1;
                const int dy = 2 - ((ky + 1) >> 1);
#pragma unroll
                for (int kx = 0; kx < 4; ++kx) {
                    const int rx = (kx + 1) & 1;
                    const int dx = 2 - ((kx + 1) >> 1);
                    const float v = in9[dy * 3 + dx];
                    const int po = ry * 2 + rx;
                    const float4* wp = (const float4*)&sw[(ic_l * 16 + ky * 4 + kx) * OCT];
#pragma unroll
                    for (int q4 = 0; q4 < OCT / 4; ++q4) {
                        float4 wv = wp[q4];
                        acc[po * OCT + q4 * 4 + 0] = fmaf(wv.x, v, acc[po * OCT + q4 * 4 + 0]);
                        acc[po * OCT + q4 * 4 + 1] = fmaf(wv.y, v, acc[po * OCT + q4 * 4 + 1]);
                        acc[po * OCT + q4 * 4 + 2] = fmaf(wv.z, v, acc[po * OCT + q4 * 4 + 2]);
                        acc[po * OCT + q4 * 4 + 3] = fmaf(wv.w, v, acc[po * OCT + q4 * 4 + 3]);
                    }
                }
            }
        }
    }
#pragma unroll
    for (int po = 0; po < 4; ++po) {
        const int ry = po >> 1, rx = po & 1;
        const int oy = 2 * A + ry, ox = 2 * C + rx;
#pragma unroll
        for (int j = 0; j < OCT; ++j) {
            float r = acc[po * OCT + j] + bias[oc0 + j];
            r = actf<ACT>(r);
            out[((size_t)(n * COUT + oc0 + j) * HOUT + oy) * WOUT + ox] = r;
        }
    }
}

// ---------------------------------------------------------------------------
// Residual VQ, register-blocked: lane-pair (lanes 2k,2k+1) owns 2 tokens;
// lane holds dims h*32..h*32+31 of both. Per code: 8 broadcast ds_read_b128 +
// 64 FMA (4 indep chains). Block=128, grid=512 (2 blocks/CU, 4 waves/CU).
// Strict < keeps first argmin (matches jnp.argmin).
// ---------------------------------------------------------------------------
__launch_bounds__(128)
__global__ void rvq_k(const float* __restrict__ z, const float* __restrict__ cb,
                      float* __restrict__ q, float* __restrict__ idx_out,
                      float* __restrict__ loss_acc)
{
    __shared__ float scb[128 * 64];
    __shared__ float ssc[128];
    const int tid = threadIdx.x;
    const int h = tid & 1;                  // dim half
    const int pr = tid >> 1;                // pair 0..63
    const int t0 = blockIdx.x * 128 + pr * 2;
    const int t1 = t0 + 1;

    float z0[32], z1[32], r0[32], r1[32];
    {
        const float4* zp0 = (const float4*)(z + (size_t)t0 * 64 + h * 32);
        const float4* zp1 = (const float4*)(z + (size_t)t1 * 64 + h * 32);
#pragma unroll
        for (int i = 0; i < 8; ++i) {
            float4 a = zp0[i], b = zp1[i];
            z0[4*i+0]=a.x; z0[4*i+1]=a.y; z0[4*i+2]=a.z; z0[4*i+3]=a.w;
            z1[4*i+0]=b.x; z1[4*i+1]=b.y; z1[4*i+2]=b.z; z1[4*i+3]=b.w;
            r0[4*i+0]=a.x; r0[4*i+1]=a.y; r0[4*i+2]=a.z; r0[4*i+3]=a.w;
            r1[4*i+0]=b.x; r1[4*i+1]=b.y; r1[4*i+2]=b.z; r1[4*i+3]=b.w;
        }
    }

    for (int s = 0; s < 4; ++s) {
        // |r|^2 for both tokens (half-sums, completed via pair shuffle)
        float sa = 0.f, sb = 0.f;
#pragma unroll
        for (int i = 0; i < 32; ++i) { sa = fmaf(r0[i], r0[i], sa); sb = fmaf(r1[i], r1[i], sb); }
        sa += __shfl_xor(sa, 1, 64);
        sb += __shfl_xor(sb, 1, 64);

        float dmin0 = 3.4e38f, dmin1 = 3.4e38f;
        int best0 = 0, best1 = 0;
        for (int pass = 0; pass < 4; ++pass) {
            __syncthreads();
            const float* src = cb + ((size_t)s * 512 + pass * 128) * 64;
            for (int i2 = tid; i2 < 128 * 64 / 4; i2 += 128)
                ((float4*)scb)[i2] = ((const float4*)src)[i2];
            {
                const float* cc = src + (size_t)tid * 64;
                float a = 0.f;
#pragma unroll
                for (int i = 0; i < 64; ++i) a = fmaf(cc[i], cc[i], a);
                ssc[tid] = a;
            }
            __syncthreads();
#pragma unroll 1
            for (int kk = 0; kk < 128; ++kk) {
                const float4* cp = (const float4*)&scb[kk * 64 + h * 32];
                float a0 = 0.f, a1 = 0.f, b0 = 0.f, b1 = 0.f;
#pragma unroll
                for (int i = 0; i < 8; ++i) {
                    const float4 c = cp[i];
                    if (i & 1) {
                        a1 = fmaf(r0[4*i+0], c.x, a1); a1 = fmaf(r0[4*i+1], c.y, a1);
                        a1 = fmaf(r0[4*i+2], c.z, a1); a1 = fmaf(r0[4*i+3], c.w, a1);
                        b1 = fmaf(r1[4*i+0], c.x, b1); b1 = fmaf(r1[4*i+1], c.y, b1);
                        b1 = fmaf(r1[4*i+2], c.z, b1); b1 = fmaf(r1[4*i+3], c.w, b1);
                    } else {
                        a0 = fmaf(r0[4*i+0], c.x, a0); a0 = fmaf(r0[4*i+1], c.y, a0);
                        a0 = fmaf(r0[4*i+2], c.z, a0); a0 = fmaf(r0[4*i+3], c.w, a0);
                        b0 = fmaf(r1[4*i+0], c.x, b0); b0 = fmaf(r1[4*i+1], c.y, b0);
                        b0 = fmaf(r1[4*i+2], c.z, b0); b0 = fmaf(r1[4*i+3], c.w, b0);
                    }
                }
                float dot0 = a0 + a1, dot1 = b0 + b1;
                dot0 += __shfl_xor(dot0, 1, 64);
                dot1 += __shfl_xor(dot1, 1, 64);
                const float sc = ssc[kk];
                const float d0 = fmaf(-2.f, dot0, sa) + sc;
                const float d1 = fmaf(-2.f, dot1, sb) + sc;
                const int kg = pass * 128 + kk;
                if (d0 < dmin0) { dmin0 = d0; best0 = kg; }
                if (d1 < dmin1) { dmin1 = d1; best1 = kg; }
            }
        }
        // loss: sum of dmin over tokens (count each token once -> h==0 lanes)
        float lv = (h == 0) ? (dmin0 + dmin1) : 0.f;
#pragma unroll
        for (int off = 32; off; off >>= 1) lv += __shfl_down(lv, off, 64);
        if ((tid & 63) == 0) atomicAdd(&loss_acc[s], lv);

        if (h == 0) {
            idx_out[(size_t)t0 * 4 + s] = (float)best0;
            idx_out[(size_t)t1 * 4 + s] = (float)best1;
        }

        const float4* cb0 = (const float4*)(cb + ((size_t)s * 512 + best0) * 64 + h * 32);
        const float4* cb1 = (const float4*)(cb + ((size_t)s * 512 + best1) * 64 + h * 32);
#pragma unroll
        for (int i = 0; i < 8; ++i) {
            const float4 c0 = cb0[i], c1 = cb1[i];
            r0[4*i+0] -= c0.x; r0[4*i+1] -= c0.y; r0[4*i+2] -= c0.z; r0[4*i+3] -= c0.w;
            r1[4*i+0] -= c1.x; r1[4*i+1] -= c1.y; r1[4*i+2] -= c1.z; r1[4*i+3] -= c1.w;
        }
    }
    // q_out = z - r_final, NCHW layout
    {
        const int n0 = t0 >> 12, p0 = t0 & 4095;
        const int n1 = t1 >> 12, p1 = t1 & 4095;
        float* qp0 = q + (size_t)n0 * 64 * 4096 + p0;
        float* qp1 = q + (size_t)n1 * 64 * 4096 + p1;
#pragma unroll
        for (int i = 0; i < 32; ++i) {
            qp0[(size_t)(h * 32 + i) * 4096] = z0[i] - r0[i];
            qp1[(size_t)(h * 32 + i) * 4096] = z1[i] - r1[i];
        }
    }
}

__global__ void init_k(float* loss_acc) {
    if (threadIdx.x < 4) loss_acc[threadIdx.x] = 0.f;
}
__global__ void fin_k(const float* __restrict__ loss_acc, float* __restrict__ out_loss) {
    if (threadIdx.x < 4)
        out_loss[threadIdx.x] = loss_acc[threadIdx.x] * (0.25f / 4194304.f); // BETA/(N*D)
}

// ---------------------------------------------------------------------------
extern "C" void kernel_launch(void* const* d_in, const int* in_sizes, int n_in,
                              void* d_out, int out_size, void* d_ws, size_t ws_size,
                              hipStream_t stream)
{
    const float* x    = (const float*)d_in[0];
    const float* e1w  = (const float*)d_in[1];  const float* e1b = (const float*)d_in[2];
    const float* e2w  = (const float*)d_in[3];  const float* e2b = (const float*)d_in[4];
    const float* e3w  = (const float*)d_in[5];  const float* e3b = (const float*)d_in[6];
    const float* r1aw = (const float*)d_in[7];  const float* r1bw = (const float*)d_in[8];
    const float* r2aw = (const float*)d_in[9];  const float* r2bw = (const float*)d_in[10];
    const float* e4w  = (const float*)d_in[11]; const float* e4b = (const float*)d_in[12];
    const float* cbs  = (const float*)d_in[13];
    const float* d1w  = (const float*)d_in[14]; const float* d1b = (const float*)d_in[15];
    const float* dr1aw= (const float*)d_in[16]; const float* dr1bw = (const float*)d_in[17];
    const float* dr2aw= (const float*)d_in[18]; const float* dr2bw = (const float*)d_in[19];
    const float* dt1w = (const float*)d_in[20]; const float* dt1b = (const float*)d_in[21];
    const float* dt2w = (const float*)d_in[22]; const float* dt2b = (const float*)d_in[23];

    float* out = (float*)d_out;
    float* ws  = (float*)d_ws;

    float* BIG = ws;                    // 16.78M floats (e1 out / dt1 out)
    float* P2  = BIG;
    float* P3  = BIG + 8388608;
    float* P1  = ws + 16777216;
    float* Z   = ws + 25165824;
    float* Q   = ws + 29360128;
    float* LACC= ws + 33554432;

    float* out_recons = out;                    // 16*4*256*256 = 4194304
    float* out_idx    = out + 4194304;          // 16*64*64*4   = 262144
    float* out_loss   = out + 4194304 + 262144; // 4

    init_k<<<1, 64, 0, stream>>>(LACC);

    // ---- encoder ----
    conv_k<4, 64, 4, 2, 1, 256, 256, 128, 128, 4, 1, 2, true>
        <<<dim3(64, 4, 16), 256, 0, stream>>>(x, e1w, e1b, BIG);
    conv_k<64, 128, 4, 2, 1, 128, 128, 64, 64, 16, 2, 2, true>
        <<<dim3(8, 8, 16), 256, 0, stream>>>(BIG, e2w, e2b, P1);
    conv_k<128, 128, 3, 1, 1, 64, 64, 64, 64, 16, 2, 2, true>
        <<<dim3(8, 8, 16), 256, 0, stream>>>(P1, e3w, e3b, P2);
    conv_k<128, 128, 3, 1, 1, 64, 64, 64, 64, 16, 2, 1, false>
        <<<dim3(8, 8, 16), 256, 0, stream>>>(P2, r1aw, nullptr, P3);
    conv1x1_k<128, 128, 0, false, false, true, false>
        <<<dim3(8, 8, 16), 256, 0, stream>>>(P3, r1bw, nullptr, P2, P1);
    conv_k<128, 128, 3, 1, 1, 64, 64, 64, 64, 16, 2, 1, false>
        <<<dim3(8, 8, 16), 256, 0, stream>>>(P1, r2aw, nullptr, P3);
    conv1x1_k<128, 128, 0, false, false, true, false>
        <<<dim3(8, 8, 16), 256, 0, stream>>>(P3, r2bw, nullptr, P1, P2);
    conv1x1_k<128, 64, 2, true, true, false, true>
        <<<dim3(8, 4, 16), 256, 0, stream>>>(P2, e4w, e4b, nullptr, Z);

    // ---- residual VQ ----
    rvq_k<<<512, 128, 0, stream>>>(Z, cbs, Q, out_idx, LACC);
    fin_k<<<1, 64, 0, stream>>>(LACC, out_loss);

    // ---- decoder ----
    conv_k<64, 128, 3, 1, 1, 64, 64, 64, 64, 16, 2, 2, true>
        <<<dim3(8, 8, 16), 256, 0, stream>>>(Q, d1w, d1b, P1);
    conv_k<128, 128, 3, 1, 1, 64, 64, 64, 64, 16, 2, 1, false>
        <<<dim3(8, 8, 16), 256, 0, stream>>>(P1, dr1aw, nullptr, P2);
    conv1x1_k<128, 128, 0, false, false, true, false>
        <<<dim3(8, 8, 16), 256, 0, stream>>>(P2, dr1bw, nullptr, P1, P3);
    conv_k<128, 128, 3, 1, 1, 64, 64, 64, 64, 16, 2, 1, false>
        <<<dim3(8, 8, 16), 256, 0, stream>>>(P3, dr2aw, nullptr, P2);
    conv1x1_k<128, 128, 0, false, false, true, false>
        <<<dim3(8, 8, 16), 256, 0, stream>>>(P2, dr2bw, nullptr, P3, P1);
    convt_k<128, 64, 16, 64, 8, 2, true>
        <<<dim3(16, 4, 16), 256, 0, stream>>>(P1, dt1w, dt1b, BIG);
    convt_k<64, 4, 4, 128, 16, 1, false>
        <<<dim3(64, 1, 16), 256, 0, stream>>>(BIG, dt2w, dt2b, out_recons);
}

// Round 7
// 3040.825 us; speedup vs baseline: 1.0346x; 1.0346x over previous
//
#include <hip/hip_runtime.h>
#include <cstddef>

// ---------------------------------------------------------------------------
// RQ-VAE forward on MI355X. Round 7: R5-validated config + rvq norm-table fix.
// R6 post-mortem: T=2 halved waves/CU -> latency-exposed (650us, 31% VALU).
// Real rvq bottleneck: per-pass codebook-norm recompute = 64 scalar 64-way-
// uncoalesced global loads/lane -> ~524k L1 transactions/CU (~218us). Fix:
// norms precomputed once (norm_k), rvq loads them coalesced.
// ---------------------------------------------------------------------------

template<int ACT> __device__ __forceinline__ float actf(float v) {
    if constexpr (ACT == 1) return v > 0.f ? v : 0.f;            // relu
    else if constexpr (ACT == 2) return v > 0.f ? v : 0.01f * v; // leaky relu
    else return v;
}
__device__ __forceinline__ float lrelu_in(float v) { return v > 0.f ? v : 0.01f * v; }

// ---------------------------------------------------------------------------
// Direct conv: thread = NPY vertical output pixels x 16 output channels.
// (validated R3/R5)
// ---------------------------------------------------------------------------
template<int CIN, int COUT, int K, int S, int P, int HIN, int WIN, int HOUT, int WOUT,
         int ICC, int NPY, int ACT, bool BIAS>
__launch_bounds__(256, 4)
__global__ void conv_k(const float* __restrict__ in, const float* __restrict__ w,
                       const float* __restrict__ bias, float* __restrict__ out)
{
    constexpr int K2 = K * K;
    constexpr int NR = S * (NPY - 1) + K;
    constexpr int BH = 16 * NPY;
    __shared__ float sw[ICC * K2 * 16];
    const int tid = threadIdx.x;
    const int tx = tid & 15, ty = tid >> 4;
    constexpr int TW = WOUT / 16;
    const int bx = blockIdx.x % TW, by = blockIdx.x / TW;
    const int ox = bx * 16 + tx;
    const int oy0 = by * BH + ty * NPY;
    const int oc0 = blockIdx.y * 16;
    const int n = blockIdx.z;
    const int ix0 = ox * S - P, iy0 = oy0 * S - P;

    int ro[NR]; float mr[NR];
#pragma unroll
    for (int r = 0; r < NR; ++r) {
        const int iy = iy0 + r;
        const bool v = (iy >= 0) && (iy < HIN);
        ro[r] = v ? iy * WIN : 0;
        mr[r] = v ? 1.f : 0.f;
    }
    int co[K]; float mc[K];
#pragma unroll
    for (int c = 0; c < K; ++c) {
        const int ix = ix0 + c;
        const bool v = (ix >= 0) && (ix < WIN);
        co[c] = v ? ix : 0;
        mc[c] = v ? 1.f : 0.f;
    }

    float acc[NPY][16];
#pragma unroll
    for (int py = 0; py < NPY; ++py)
#pragma unroll
        for (int j = 0; j < 16; ++j) acc[py][j] = 0.f;

    for (int ic0 = 0; ic0 < CIN; ic0 += ICC) {
        __syncthreads();
        for (int t = tid; t < ICC * K2 * 16; t += 256) {
            int oc_l = t & 15, r = t >> 4, k = r % K2, ic_l = r / K2;
            sw[(ic_l * K2 + k) * 16 + oc_l] =
                w[((size_t)(oc0 + oc_l) * CIN + ic0 + ic_l) * K2 + k];
        }
        __syncthreads();
#pragma unroll 1
        for (int ic_l = 0; ic_l < ICC; ++ic_l) {
            const float* ip = in + (size_t)(n * CIN + ic0 + ic_l) * HIN * WIN;
            float patch[NR][K];
#pragma unroll
            for (int r = 0; r < NR; ++r)
#pragma unroll
                for (int c = 0; c < K; ++c)
                    patch[r][c] = ip[ro[r] + co[c]] * (mr[r] * mc[c]);
            const float* swp = &sw[ic_l * K2 * 16];
#pragma unroll
            for (int ky = 0; ky < K; ++ky) {
#pragma unroll
                for (int kx = 0; kx < K; ++kx) {
                    const float4* wp = (const float4*)&swp[(ky * K + kx) * 16];
                    float4 w0 = wp[0], w1 = wp[1], w2 = wp[2], w3 = wp[3];
#pragma unroll
                    for (int py = 0; py < NPY; ++py) {
                        const float v = patch[py * S + ky][kx];
                        acc[py][0]  = fmaf(w0.x, v, acc[py][0]);
                        acc[py][1]  = fmaf(w0.y, v, acc[py][1]);
                        acc[py][2]  = fmaf(w0.z, v, acc[py][2]);
                        acc[py][3]  = fmaf(w0.w, v, acc[py][3]);
                        acc[py][4]  = fmaf(w1.x, v, acc[py][4]);
                        acc[py][5]  = fmaf(w1.y, v, acc[py][5]);
                        acc[py][6]  = fmaf(w1.z, v, acc[py][6]);
                        acc[py][7]  = fmaf(w1.w, v, acc[py][7]);
                        acc[py][8]  = fmaf(w2.x, v, acc[py][8]);
                        acc[py][9]  = fmaf(w2.y, v, acc[py][9]);
                        acc[py][10] = fmaf(w2.z, v, acc[py][10]);
                        acc[py][11] = fmaf(w2.w, v, acc[py][11]);
                        acc[py][12] = fmaf(w3.x, v, acc[py][12]);
                        acc[py][13] = fmaf(w3.y, v, acc[py][13]);
                        acc[py][14] = fmaf(w3.z, v, acc[py][14]);
                        acc[py][15] = fmaf(w3.w, v, acc[py][15]);
                    }
                }
            }
        }
    }
#pragma unroll
    for (int py = 0; py < NPY; ++py) {
#pragma unroll
        for (int j = 0; j < 16; ++j) {
            float r = acc[py][j];
            if (BIAS) r += bias[oc0 + j];
            r = actf<ACT>(r);
            out[((size_t)(n * COUT + oc0 + j) * HOUT + oy0 + py) * WOUT + ox] = r;
        }
    }
}

// ---------------------------------------------------------------------------
// 1x1 conv over 64x64 maps (HW=4096), 2 pixels per thread. (validated R3/R5)
// ---------------------------------------------------------------------------
template<int CIN, int COUT, int ACT, bool BIAS, bool INL, bool RESID, bool TOK>
__launch_bounds__(256, 4)
__global__ void conv1x1_k(const float* __restrict__ in, const float* __restrict__ w,
                          const float* __restrict__ bias, const float* __restrict__ resid,
                          float* __restrict__ out)
{
    constexpr int HW = 4096;
    __shared__ float sw[16 * CIN];
    const int tid = threadIdx.x;
    const int p0 = blockIdx.x * 512 + tid;
    const int p1 = p0 + 256;
    const int oc0 = blockIdx.y * 16;
    const int n = blockIdx.z;

    for (int t = tid; t < 16 * CIN; t += 256) {
        int oc_l = t & 15, ic = t >> 4;
        sw[ic * 16 + oc_l] = w[(size_t)(oc0 + oc_l) * CIN + ic];
    }
    __syncthreads();

    float acc[2][16];
#pragma unroll
    for (int p = 0; p < 2; ++p)
#pragma unroll
        for (int j = 0; j < 16; ++j) acc[p][j] = 0.f;

    const float* ip = in + (size_t)n * CIN * HW;
#pragma unroll 2
    for (int ic = 0; ic < CIN; ++ic) {
        float v0 = ip[(size_t)ic * HW + p0];
        float v1 = ip[(size_t)ic * HW + p1];
        if (INL) { v0 = lrelu_in(v0); v1 = lrelu_in(v1); }
        const float4* wp = (const float4*)&sw[ic * 16];
#pragma unroll
        for (int q4 = 0; q4 < 4; ++q4) {
            float4 wv = wp[q4];
            acc[0][q4 * 4 + 0] = fmaf(wv.x, v0, acc[0][q4 * 4 + 0]);
            acc[0][q4 * 4 + 1] = fmaf(wv.y, v0, acc[0][q4 * 4 + 1]);
            acc[0][q4 * 4 + 2] = fmaf(wv.z, v0, acc[0][q4 * 4 + 2]);
            acc[0][q4 * 4 + 3] = fmaf(wv.w, v0, acc[0][q4 * 4 + 3]);
            acc[1][q4 * 4 + 0] = fmaf(wv.x, v1, acc[1][q4 * 4 + 0]);
            acc[1][q4 * 4 + 1] = fmaf(wv.y, v1, acc[1][q4 * 4 + 1]);
            acc[1][q4 * 4 + 2] = fmaf(wv.z, v1, acc[1][q4 * 4 + 2]);
            acc[1][q4 * 4 + 3] = fmaf(wv.w, v1, acc[1][q4 * 4 + 3]);
        }
    }
#pragma unroll
    for (int p = 0; p < 2; ++p) {
        const int pix = p == 0 ? p0 : p1;
#pragma unroll
        for (int j = 0; j < 16; ++j) {
            float r = acc[p][j];
            if (BIAS) r += bias[oc0 + j];
            r = actf<ACT>(r);
            if (RESID) r += resid[((size_t)(n * COUT + oc0 + j)) * HW + pix];
            if (TOK)
                out[((size_t)n * HW + pix) * COUT + oc0 + j] = r;
            else
                out[((size_t)(n * COUT + oc0 + j)) * HW + pix] = r;
        }
    }
}

// ---------------------------------------------------------------------------
// ConvTranspose2d k=4 s=2 p=1, parity decomposition. (validated R2/R5)
// ---------------------------------------------------------------------------
template<int CIN, int COUT, int OCT, int HIN, int ICC, int ACT, bool INL>
__launch_bounds__(256, 3)
__global__ void convt_k(const float* __restrict__ in, const float* __restrict__ w,
                        const float* __restrict__ bias, float* __restrict__ out)
{
    constexpr int WIN = HIN, HOUT = 2 * HIN, WOUT = 2 * HIN;
    __shared__ float sw[ICC * 16 * OCT];
    const int tid = threadIdx.x;
    const int tx = tid & 15, ty = tid >> 4;
    constexpr int TBW = WOUT / 32;
    const int bx = blockIdx.x % TBW, by = blockIdx.x / TBW;
    const int A = by * 16 + ty;
    const int C = bx * 16 + tx;
    const int oc0 = blockIdx.y * OCT;
    const int n = blockIdx.z;

    int offs[9]; float msk[9];
#pragma unroll
    for (int dy = 0; dy < 3; ++dy) {
#pragma unroll
        for (int dx = 0; dx < 3; ++dx) {
            const int iy = A - 1 + dy, ix = C - 1 + dx;
            const bool v = (iy >= 0) && (iy < HIN) && (ix >= 0) && (ix < WIN);
            offs[dy * 3 + dx] = v ? iy * WIN + ix : 0;
            msk[dy * 3 + dx] = v ? 1.f : 0.f;
        }
    }

    float acc[4 * OCT];
#pragma unroll
    for (int j = 0; j < 4 * OCT; ++j) acc[j] = 0.f;

    for (int ic0 = 0; ic0 < CIN; ic0 += ICC) {
        __syncthreads();
        for (int t = tid; t < ICC * 16 * OCT; t += 256) {
            int oc_l = t % OCT, r = t / OCT, k = r & 15, ic_l = r >> 4;
            sw[(ic_l * 16 + k) * OCT + oc_l] =
                w[((size_t)(ic0 + ic_l) * COUT + oc0 + oc_l) * 16 + k];
        }
        __syncthreads();
#pragma unroll 1
        for (int ic_l = 0; ic_l < ICC; ++ic_l) {
            const float* ip = in + (size_t)(n * CIN + ic0 + ic_l) * HIN * WIN;
            float in9[9];
#pragma unroll
            for (int j = 0; j < 9; ++j) {
                float v = ip[offs[j]] * msk[j];
                if (INL) v = lrelu_in(v);
                in9[j] = v;
            }
#pragma unroll
            for (int ky = 0; ky < 4; ++ky) {
                const int ry = (ky + 1) & 1;
                const int dy = 2 - ((ky + 1) >> 1);
#pragma unroll
                for (int kx = 0; kx < 4; ++kx) {
                    const int rx = (kx + 1) & 1;
                    const int dx = 2 - ((kx + 1) >> 1);
                    const float v = in9[dy * 3 + dx];
                    const int po = ry * 2 + rx;
                    const float4* wp = (const float4*)&sw[(ic_l * 16 + ky * 4 + kx) * OCT];
#pragma unroll
                    for (int q4 = 0; q4 < OCT / 4; ++q4) {
                        float4 wv = wp[q4];
                        acc[po * OCT + q4 * 4 + 0] = fmaf(wv.x, v, acc[po * OCT + q4 * 4 + 0]);
                        acc[po * OCT + q4 * 4 + 1] = fmaf(wv.y, v, acc[po * OCT + q4 * 4 + 1]);
                        acc[po * OCT + q4 * 4 + 2] = fmaf(wv.z, v, acc[po * OCT + q4 * 4 + 2]);
                        acc[po * OCT + q4 * 4 + 3] = fmaf(wv.w, v, acc[po * OCT + q4 * 4 + 3]);
                    }
                }
            }
        }
    }
#pragma unroll
    for (int po = 0; po < 4; ++po) {
        const int ry = po >> 1, rx = po & 1;
        const int oy = 2 * A + ry, ox = 2 * C + rx;
#pragma unroll
        for (int j = 0; j < OCT; ++j) {
            float r = acc[po * OCT + j] + bias[oc0 + j];
            r = actf<ACT>(r);
            out[((size_t)(n * COUT + oc0 + j) * HOUT + oy) * WOUT + ox] = r;
        }
    }
}

// ---------------------------------------------------------------------------
// Codebook norms, precomputed once: nrm[c] = |cb_c|^2 for all 4*512 codes.
// ---------------------------------------------------------------------------
__global__ void norm_k(const float* __restrict__ cb, float* __restrict__ nrm) {
    const int c = blockIdx.x * 256 + threadIdx.x;   // 0..2047
    const float4* p = (const float4*)(cb + (size_t)c * 64);
    float a0 = 0.f, a1 = 0.f, a2 = 0.f, a3 = 0.f;
#pragma unroll
    for (int i = 0; i < 16; ++i) {
        float4 v = p[i];
        a0 = fmaf(v.x, v.x, a0); a1 = fmaf(v.y, v.y, a1);
        a2 = fmaf(v.z, v.z, a2); a3 = fmaf(v.w, v.w, a3);
    }
    nrm[c] = (a0 + a1) + (a2 + a3);
}

// ---------------------------------------------------------------------------
// Residual VQ: 2 lanes/token, block=128, grid=1024 (validated R3/R5), with
// per-pass norms loaded from the precomputed table (1 coalesced load) instead
// of the 64 uncoalesced scalar loads per lane.
// ---------------------------------------------------------------------------
__launch_bounds__(128)
__global__ void rvq_k(const float* __restrict__ z, const float* __restrict__ cb,
                      const float* __restrict__ nrm,
                      float* __restrict__ q, float* __restrict__ idx_out,
                      float* __restrict__ loss_acc)
{
    __shared__ float scb[128 * 64];
    __shared__ float ssc[128];
    const int tid = threadIdx.x;
    const int h = tid & 1;
    const int tloc = tid >> 1;
    const int t = blockIdx.x * 64 + tloc;

    float zr[32], r[32];
    const float4* zp = (const float4*)(z + (size_t)t * 64 + h * 32);
#pragma unroll
    for (int i = 0; i < 8; ++i) {
        float4 v = zp[i];
        zr[4 * i + 0] = v.x; zr[4 * i + 1] = v.y; zr[4 * i + 2] = v.z; zr[4 * i + 3] = v.w;
        r[4 * i + 0] = v.x;  r[4 * i + 1] = v.y;  r[4 * i + 2] = v.z;  r[4 * i + 3] = v.w;
    }

    for (int s = 0; s < 4; ++s) {
        float s0 = 0.f, s1 = 0.f, s2 = 0.f, s3 = 0.f;
#pragma unroll
        for (int i = 0; i < 32; i += 4) {
            s0 = fmaf(r[i + 0], r[i + 0], s0);
            s1 = fmaf(r[i + 1], r[i + 1], s1);
            s2 = fmaf(r[i + 2], r[i + 2], s2);
            s3 = fmaf(r[i + 3], r[i + 3], s3);
        }
        float sr2 = (s0 + s1) + (s2 + s3);
        sr2 += __shfl_xor(sr2, 1, 64);

        float dmin = 3.4e38f;
        int best = 0;
        for (int pass = 0; pass < 4; ++pass) {
            __syncthreads();
            const float* src = cb + ((size_t)s * 512 + pass * 128) * 64;
            for (int i2 = tid; i2 < 128 * 64 / 4; i2 += 128)
                ((float4*)scb)[i2] = ((const float4*)src)[i2];
            ssc[tid] = nrm[(size_t)s * 512 + pass * 128 + tid];
            __syncthreads();
#pragma unroll 2
            for (int kk = 0; kk < 128; ++kk) {
                const float4* cp = (const float4*)&scb[kk * 64 + h * 32];
                float d0 = 0.f, d1 = 0.f, d2 = 0.f, d3 = 0.f;
#pragma unroll
                for (int i = 0; i < 8; ++i) {
                    float4 c = cp[i];
                    d0 = fmaf(r[4 * i + 0], c.x, d0);
                    d1 = fmaf(r[4 * i + 1], c.y, d1);
                    d2 = fmaf(r[4 * i + 2], c.z, d2);
                    d3 = fmaf(r[4 * i + 3], c.w, d3);
                }
                float dot = (d0 + d1) + (d2 + d3);
                dot += __shfl_xor(dot, 1, 64);
                const float d = fmaf(-2.f, dot, sr2) + ssc[kk];
                if (d < dmin) { dmin = d; best = pass * 128 + kk; }
            }
        }
        float lv = (h == 0) ? dmin : 0.f;
#pragma unroll
        for (int off = 32; off; off >>= 1) lv += __shfl_down(lv, off, 64);
        if ((tid & 63) == 0) atomicAdd(&loss_acc[s], lv);

        if (h == 0) idx_out[(size_t)t * 4 + s] = (float)best;

        const float4* cbest = (const float4*)(cb + ((size_t)s * 512 + best) * 64 + h * 32);
#pragma unroll
        for (int i = 0; i < 8; ++i) {
            float4 c = cbest[i];
            r[4 * i + 0] -= c.x; r[4 * i + 1] -= c.y;
            r[4 * i + 2] -= c.z; r[4 * i + 3] -= c.w;
        }
    }
    const int n = t >> 12, pix = t & 4095;
    float* qp = q + (size_t)n * 64 * 4096 + pix;
#pragma unroll
    for (int i = 0; i < 32; ++i)
        qp[(size_t)(h * 32 + i) * 4096] = zr[i] - r[i];
}

__global__ void init_k(float* loss_acc) {
    if (threadIdx.x < 4) loss_acc[threadIdx.x] = 0.f;
}
__global__ void fin_k(const float* __restrict__ loss_acc, float* __restrict__ out_loss) {
    if (threadIdx.x < 4)
        out_loss[threadIdx.x] = loss_acc[threadIdx.x] * (0.25f / 4194304.f); // BETA/(N*D)
}

// ---------------------------------------------------------------------------
extern "C" void kernel_launch(void* const* d_in, const int* in_sizes, int n_in,
                              void* d_out, int out_size, void* d_ws, size_t ws_size,
                              hipStream_t stream)
{
    const float* x    = (const float*)d_in[0];
    const float* e1w  = (const float*)d_in[1];  const float* e1b = (const float*)d_in[2];
    const float* e2w  = (const float*)d_in[3];  const float* e2b = (const float*)d_in[4];
    const float* e3w  = (const float*)d_in[5];  const float* e3b = (const float*)d_in[6];
    const float* r1aw = (const float*)d_in[7];  const float* r1bw = (const float*)d_in[8];
    const float* r2aw = (const float*)d_in[9];  const float* r2bw = (const float*)d_in[10];
    const float* e4w  = (const float*)d_in[11]; const float* e4b = (const float*)d_in[12];
    const float* cbs  = (const float*)d_in[13];
    const float* d1w  = (const float*)d_in[14]; const float* d1b = (const float*)d_in[15];
    const float* dr1aw= (const float*)d_in[16]; const float* dr1bw = (const float*)d_in[17];
    const float* dr2aw= (const float*)d_in[18]; const float* dr2bw = (const float*)d_in[19];
    const float* dt1w = (const float*)d_in[20]; const float* dt1b = (const float*)d_in[21];
    const float* dt2w = (const float*)d_in[22]; const float* dt2b = (const float*)d_in[23];

    float* out = (float*)d_out;
    float* ws  = (float*)d_ws;

    float* BIG = ws;                    // 16.78M floats (e1 out / dt1 out)
    float* P2  = BIG;
    float* P3  = BIG + 8388608;
    float* P1  = ws + 16777216;
    float* Z   = ws + 25165824;
    float* Q   = ws + 29360128;
    float* LACC= ws + 33554432;         // 4 floats
    float* NRM = ws + 33554448;         // 2048 floats

    float* out_recons = out;                    // 16*4*256*256 = 4194304
    float* out_idx    = out + 4194304;          // 16*64*64*4   = 262144
    float* out_loss   = out + 4194304 + 262144; // 4

    init_k<<<1, 64, 0, stream>>>(LACC);
    norm_k<<<8, 256, 0, stream>>>(cbs, NRM);

    // ---- encoder ----
    conv_k<4, 64, 4, 2, 1, 256, 256, 128, 128, 4, 1, 2, true>
        <<<dim3(64, 4, 16), 256, 0, stream>>>(x, e1w, e1b, BIG);
    conv_k<64, 128, 4, 2, 1, 128, 128, 64, 64, 16, 2, 2, true>
        <<<dim3(8, 8, 16), 256, 0, stream>>>(BIG, e2w, e2b, P1);
    conv_k<128, 128, 3, 1, 1, 64, 64, 64, 64, 16, 2, 2, true>
        <<<dim3(8, 8, 16), 256, 0, stream>>>(P1, e3w, e3b, P2);
    conv_k<128, 128, 3, 1, 1, 64, 64, 64, 64, 16, 2, 1, false>
        <<<dim3(8, 8, 16), 256, 0, stream>>>(P2, r1aw, nullptr, P3);
    conv1x1_k<128, 128, 0, false, false, true, false>
        <<<dim3(8, 8, 16), 256, 0, stream>>>(P3, r1bw, nullptr, P2, P1);
    conv_k<128, 128, 3, 1, 1, 64, 64, 64, 64, 16, 2, 1, false>
        <<<dim3(8, 8, 16), 256, 0, stream>>>(P1, r2aw, nullptr, P3);
    conv1x1_k<128, 128, 0, false, false, true, false>
        <<<dim3(8, 8, 16), 256, 0, stream>>>(P3, r2bw, nullptr, P1, P2);
    conv1x1_k<128, 64, 2, true, true, false, true>
        <<<dim3(8, 4, 16), 256, 0, stream>>>(P2, e4w, e4b, nullptr, Z);

    // ---- residual VQ ----
    rvq_k<<<1024, 128, 0, stream>>>(Z, cbs, NRM, Q, out_idx, LACC);
    fin_k<<<1, 64, 0, stream>>>(LACC, out_loss);

    // ---- decoder ----
    conv_k<64, 128, 3, 1, 1, 64, 64, 64, 64, 16, 2, 2, true>
        <<<dim3(8, 8, 16), 256, 0, stream>>>(Q, d1w, d1b, P1);
    conv_k<128, 128, 3, 1, 1, 64, 64, 64, 64, 16, 2, 1, false>
        <<<dim3(8, 8, 16), 256, 0, stream>>>(P1, dr1aw, nullptr, P2);
    conv1x1_k<128, 128, 0, false, false, true, false>
        <<<dim3(8, 8, 16), 256, 0, stream>>>(P2, dr1bw, nullptr, P1, P3);
    conv_k<128, 128, 3, 1, 1, 64, 64, 64, 64, 16, 2, 1, false>
        <<<dim3(8, 8, 16), 256, 0, stream>>>(P3, dr2aw, nullptr, P2);
    conv1x1_k<128, 128, 0, false, false, true, false>
        <<<dim3(8, 8, 16), 256, 0, stream>>>(P2, dr2bw, nullptr, P3, P1);
    convt_k<128, 64, 16, 64, 8, 2, true>
        <<<dim3(16, 4, 16), 256, 0, stream>>>(P1, dt1w, dt1b, BIG);
    convt_k<64, 4, 4, 128, 16, 1, false>
        <<<dim3(64, 1, 16), 256, 0, stream>>>(BIG, dt2w, dt2b, out_recons);
}

// Round 8
// 2858.025 us; speedup vs baseline: 1.1008x; 1.0640x over previous
//
#include <hip/hip_runtime.h>
#include <cstddef>

// ---------------------------------------------------------------------------
// RQ-VAE forward on MI355X. Round 8: conv FMA-density boost.
// - conv3x3 + d1: NPY 2->4 (576 FMA per 36 LDS reads/ic, VALU-bound ~72%).
// - 1x1 (128-oc): NPX=4 pixels/thread.
// - rvq at LDS-delivery roofline (~540us) - kept. e1/e2/convt kept.
// ---------------------------------------------------------------------------

template<int ACT> __device__ __forceinline__ float actf(float v) {
    if constexpr (ACT == 1) return v > 0.f ? v : 0.f;            // relu
    else if constexpr (ACT == 2) return v > 0.f ? v : 0.01f * v; // leaky relu
    else return v;
}
__device__ __forceinline__ float lrelu_in(float v) { return v > 0.f ? v : 0.01f * v; }

// ---------------------------------------------------------------------------
// Direct conv: thread = NPY vertical output pixels x 16 output channels.
// ---------------------------------------------------------------------------
template<int CIN, int COUT, int K, int S, int P, int HIN, int WIN, int HOUT, int WOUT,
         int ICC, int NPY, int ACT, bool BIAS>
__launch_bounds__(256, (NPY >= 4 ? 2 : 4))
__global__ void conv_k(const float* __restrict__ in, const float* __restrict__ w,
                       const float* __restrict__ bias, float* __restrict__ out)
{
    constexpr int K2 = K * K;
    constexpr int NR = S * (NPY - 1) + K;
    constexpr int BH = 16 * NPY;
    __shared__ float sw[ICC * K2 * 16];
    const int tid = threadIdx.x;
    const int tx = tid & 15, ty = tid >> 4;
    constexpr int TW = WOUT / 16;
    const int bx = blockIdx.x % TW, by = blockIdx.x / TW;
    const int ox = bx * 16 + tx;
    const int oy0 = by * BH + ty * NPY;
    const int oc0 = blockIdx.y * 16;
    const int n = blockIdx.z;
    const int ix0 = ox * S - P, iy0 = oy0 * S - P;

    int ro[NR]; float mr[NR];
#pragma unroll
    for (int r = 0; r < NR; ++r) {
        const int iy = iy0 + r;
        const bool v = (iy >= 0) && (iy < HIN);
        ro[r] = v ? iy * WIN : 0;
        mr[r] = v ? 1.f : 0.f;
    }
    int co[K]; float mc[K];
#pragma unroll
    for (int c = 0; c < K; ++c) {
        const int ix = ix0 + c;
        const bool v = (ix >= 0) && (ix < WIN);
        co[c] = v ? ix : 0;
        mc[c] = v ? 1.f : 0.f;
    }

    float acc[NPY][16];
#pragma unroll
    for (int py = 0; py < NPY; ++py)
#pragma unroll
        for (int j = 0; j < 16; ++j) acc[py][j] = 0.f;

    for (int ic0 = 0; ic0 < CIN; ic0 += ICC) {
        __syncthreads();
        for (int t = tid; t < ICC * K2 * 16; t += 256) {
            int oc_l = t & 15, r = t >> 4, k = r % K2, ic_l = r / K2;
            sw[(ic_l * K2 + k) * 16 + oc_l] =
                w[((size_t)(oc0 + oc_l) * CIN + ic0 + ic_l) * K2 + k];
        }
        __syncthreads();
#pragma unroll 1
        for (int ic_l = 0; ic_l < ICC; ++ic_l) {
            const float* ip = in + (size_t)(n * CIN + ic0 + ic_l) * HIN * WIN;
            float patch[NR][K];
#pragma unroll
            for (int r = 0; r < NR; ++r)
#pragma unroll
                for (int c = 0; c < K; ++c)
                    patch[r][c] = ip[ro[r] + co[c]] * (mr[r] * mc[c]);
            const float* swp = &sw[ic_l * K2 * 16];
#pragma unroll
            for (int ky = 0; ky < K; ++ky) {
#pragma unroll
                for (int kx = 0; kx < K; ++kx) {
                    const float4* wp = (const float4*)&swp[(ky * K + kx) * 16];
                    float4 w0 = wp[0], w1 = wp[1], w2 = wp[2], w3 = wp[3];
#pragma unroll
                    for (int py = 0; py < NPY; ++py) {
                        const float v = patch[py * S + ky][kx];
                        acc[py][0]  = fmaf(w0.x, v, acc[py][0]);
                        acc[py][1]  = fmaf(w0.y, v, acc[py][1]);
                        acc[py][2]  = fmaf(w0.z, v, acc[py][2]);
                        acc[py][3]  = fmaf(w0.w, v, acc[py][3]);
                        acc[py][4]  = fmaf(w1.x, v, acc[py][4]);
                        acc[py][5]  = fmaf(w1.y, v, acc[py][5]);
                        acc[py][6]  = fmaf(w1.z, v, acc[py][6]);
                        acc[py][7]  = fmaf(w1.w, v, acc[py][7]);
                        acc[py][8]  = fmaf(w2.x, v, acc[py][8]);
                        acc[py][9]  = fmaf(w2.y, v, acc[py][9]);
                        acc[py][10] = fmaf(w2.z, v, acc[py][10]);
                        acc[py][11] = fmaf(w2.w, v, acc[py][11]);
                        acc[py][12] = fmaf(w3.x, v, acc[py][12]);
                        acc[py][13] = fmaf(w3.y, v, acc[py][13]);
                        acc[py][14] = fmaf(w3.z, v, acc[py][14]);
                        acc[py][15] = fmaf(w3.w, v, acc[py][15]);
                    }
                }
            }
        }
    }
#pragma unroll
    for (int py = 0; py < NPY; ++py) {
#pragma unroll
        for (int j = 0; j < 16; ++j) {
            float r = acc[py][j];
            if (BIAS) r += bias[oc0 + j];
            r = actf<ACT>(r);
            out[((size_t)(n * COUT + oc0 + j) * HOUT + oy0 + py) * WOUT + ox] = r;
        }
    }
}

// ---------------------------------------------------------------------------
// 1x1 conv over 64x64 maps (HW=4096), NPX pixels per thread.
// ---------------------------------------------------------------------------
template<int CIN, int COUT, int NPX, int ACT, bool BIAS, bool INL, bool RESID, bool TOK>
__launch_bounds__(256, 3)
__global__ void conv1x1_k(const float* __restrict__ in, const float* __restrict__ w,
                          const float* __restrict__ bias, const float* __restrict__ resid,
                          float* __restrict__ out)
{
    constexpr int HW = 4096;
    __shared__ float sw[16 * CIN];
    const int tid = threadIdx.x;
    const int base = blockIdx.x * (256 * NPX) + tid;
    const int oc0 = blockIdx.y * 16;
    const int n = blockIdx.z;

    for (int t = tid; t < 16 * CIN; t += 256) {
        int oc_l = t & 15, ic = t >> 4;
        sw[ic * 16 + oc_l] = w[(size_t)(oc0 + oc_l) * CIN + ic];
    }
    __syncthreads();

    float acc[NPX][16];
#pragma unroll
    for (int p = 0; p < NPX; ++p)
#pragma unroll
        for (int j = 0; j < 16; ++j) acc[p][j] = 0.f;

    const float* ip = in + (size_t)n * CIN * HW;
#pragma unroll 2
    for (int ic = 0; ic < CIN; ++ic) {
        float v[NPX];
#pragma unroll
        for (int p = 0; p < NPX; ++p) {
            float t = ip[(size_t)ic * HW + base + 256 * p];
            if (INL) t = lrelu_in(t);
            v[p] = t;
        }
        const float4* wp = (const float4*)&sw[ic * 16];
#pragma unroll
        for (int q4 = 0; q4 < 4; ++q4) {
            const float4 wv = wp[q4];
#pragma unroll
            for (int p = 0; p < NPX; ++p) {
                acc[p][q4 * 4 + 0] = fmaf(wv.x, v[p], acc[p][q4 * 4 + 0]);
                acc[p][q4 * 4 + 1] = fmaf(wv.y, v[p], acc[p][q4 * 4 + 1]);
                acc[p][q4 * 4 + 2] = fmaf(wv.z, v[p], acc[p][q4 * 4 + 2]);
                acc[p][q4 * 4 + 3] = fmaf(wv.w, v[p], acc[p][q4 * 4 + 3]);
            }
        }
    }
#pragma unroll
    for (int p = 0; p < NPX; ++p) {
        const int pix = base + 256 * p;
#pragma unroll
        for (int j = 0; j < 16; ++j) {
            float r = acc[p][j];
            if (BIAS) r += bias[oc0 + j];
            r = actf<ACT>(r);
            if (RESID) r += resid[((size_t)(n * COUT + oc0 + j)) * HW + pix];
            if (TOK)
                out[((size_t)n * HW + pix) * COUT + oc0 + j] = r;
            else
                out[((size_t)(n * COUT + oc0 + j)) * HW + pix] = r;
        }
    }
}

// ---------------------------------------------------------------------------
// ConvTranspose2d k=4 s=2 p=1, parity decomposition. (validated R2/R5)
// ---------------------------------------------------------------------------
template<int CIN, int COUT, int OCT, int HIN, int ICC, int ACT, bool INL>
__launch_bounds__(256, 3)
__global__ void convt_k(const float* __restrict__ in, const float* __restrict__ w,
                        const float* __restrict__ bias, float* __restrict__ out)
{
    constexpr int WIN = HIN, HOUT = 2 * HIN, WOUT = 2 * HIN;
    __shared__ float sw[ICC * 16 * OCT];
    const int tid = threadIdx.x;
    const int tx = tid & 15, ty = tid >> 4;
    constexpr int TBW = WOUT / 32;
    const int bx = blockIdx.x % TBW, by = blockIdx.x / TBW;
    const int A = by * 16 + ty;
    const int C = bx * 16 + tx;
    const int oc0 = blockIdx.y * OCT;
    const int n = blockIdx.z;

    int offs[9]; float msk[9];
#pragma unroll
    for (int dy = 0; dy < 3; ++dy) {
#pragma unroll
        for (int dx = 0; dx < 3; ++dx) {
            const int iy = A - 1 + dy, ix = C - 1 + dx;
            const bool v = (iy >= 0) && (iy < HIN) && (ix >= 0) && (ix < WIN);
            offs[dy * 3 + dx] = v ? iy * WIN + ix : 0;
            msk[dy * 3 + dx] = v ? 1.f : 0.f;
        }
    }

    float acc[4 * OCT];
#pragma unroll
    for (int j = 0; j < 4 * OCT; ++j) acc[j] = 0.f;

    for (int ic0 = 0; ic0 < CIN; ic0 += ICC) {
        __syncthreads();
        for (int t = tid; t < ICC * 16 * OCT; t += 256) {
            int oc_l = t % OCT, r = t / OCT, k = r & 15, ic_l = r >> 4;
            sw[(ic_l * 16 + k) * OCT + oc_l] =
                w[((size_t)(ic0 + ic_l) * COUT + oc0 + oc_l) * 16 + k];
        }
        __syncthreads();
#pragma unroll 1
        for (int ic_l = 0; ic_l < ICC; ++ic_l) {
            const float* ip = in + (size_t)(n * CIN + ic0 + ic_l) * HIN * WIN;
            float in9[9];
#pragma unroll
            for (int j = 0; j < 9; ++j) {
                float v = ip[offs[j]] * msk[j];
                if (INL) v = lrelu_in(v);
                in9[j] = v;
            }
#pragma unroll
            for (int ky = 0; ky < 4; ++ky) {
                const int ry = (ky + 1) & 1;
                const int dy = 2 - ((ky + 1) >> 1);
#pragma unroll
                for (int kx = 0; kx < 4; ++kx) {
                    const int rx = (kx + 1) & 1;
                    const int dx = 2 - ((kx + 1) >> 1);
                    const float v = in9[dy * 3 + dx];
                    const int po = ry * 2 + rx;
                    const float4* wp = (const float4*)&sw[(ic_l * 16 + ky * 4 + kx) * OCT];
#pragma unroll
                    for (int q4 = 0; q4 < OCT / 4; ++q4) {
                        float4 wv = wp[q4];
                        acc[po * OCT + q4 * 4 + 0] = fmaf(wv.x, v, acc[po * OCT + q4 * 4 + 0]);
                        acc[po * OCT + q4 * 4 + 1] = fmaf(wv.y, v, acc[po * OCT + q4 * 4 + 1]);
                        acc[po * OCT + q4 * 4 + 2] = fmaf(wv.z, v, acc[po * OCT + q4 * 4 + 2]);
                        acc[po * OCT + q4 * 4 + 3] = fmaf(wv.w, v, acc[po * OCT + q4 * 4 + 3]);
                    }
                }
            }
        }
    }
#pragma unroll
    for (int po = 0; po < 4; ++po) {
        const int ry = po >> 1, rx = po & 1;
        const int oy = 2 * A + ry, ox = 2 * C + rx;
#pragma unroll
        for (int j = 0; j < OCT; ++j) {
            float r = acc[po * OCT + j] + bias[oc0 + j];
            r = actf<ACT>(r);
            out[((size_t)(n * COUT + oc0 + j) * HOUT + oy) * WOUT + ox] = r;
        }
    }
}

// ---------------------------------------------------------------------------
// Codebook norms, precomputed once.
// ---------------------------------------------------------------------------
__global__ void norm_k(const float* __restrict__ cb, float* __restrict__ nrm) {
    const int c = blockIdx.x * 256 + threadIdx.x;   // 0..2047
    const float4* p = (const float4*)(cb + (size_t)c * 64);
    float a0 = 0.f, a1 = 0.f, a2 = 0.f, a3 = 0.f;
#pragma unroll
    for (int i = 0; i < 16; ++i) {
        float4 v = p[i];
        a0 = fmaf(v.x, v.x, a0); a1 = fmaf(v.y, v.y, a1);
        a2 = fmaf(v.z, v.z, a2); a3 = fmaf(v.w, v.w, a3);
    }
    nrm[c] = (a0 + a1) + (a2 + a3);
}

// ---------------------------------------------------------------------------
// Residual VQ: 2 lanes/token, block=128, grid=1024 + norm table (validated R7).
// At LDS-delivery roofline (~540us) for this layout.
// ---------------------------------------------------------------------------
__launch_bounds__(128)
__global__ void rvq_k(const float* __restrict__ z, const float* __restrict__ cb,
                      const float* __restrict__ nrm,
                      float* __restrict__ q, float* __restrict__ idx_out,
                      float* __restrict__ loss_acc)
{
    __shared__ float scb[128 * 64];
    __shared__ float ssc[128];
    const int tid = threadIdx.x;
    const int h = tid & 1;
    const int tloc = tid >> 1;
    const int t = blockIdx.x * 64 + tloc;

    float zr[32], r[32];
    const float4* zp = (const float4*)(z + (size_t)t * 64 + h * 32);
#pragma unroll
    for (int i = 0; i < 8; ++i) {
        float4 v = zp[i];
        zr[4 * i + 0] = v.x; zr[4 * i + 1] = v.y; zr[4 * i + 2] = v.z; zr[4 * i + 3] = v.w;
        r[4 * i + 0] = v.x;  r[4 * i + 1] = v.y;  r[4 * i + 2] = v.z;  r[4 * i + 3] = v.w;
    }

    for (int s = 0; s < 4; ++s) {
        float s0 = 0.f, s1 = 0.f, s2 = 0.f, s3 = 0.f;
#pragma unroll
        for (int i = 0; i < 32; i += 4) {
            s0 = fmaf(r[i + 0], r[i + 0], s0);
            s1 = fmaf(r[i + 1], r[i + 1], s1);
            s2 = fmaf(r[i + 2], r[i + 2], s2);
            s3 = fmaf(r[i + 3], r[i + 3], s3);
        }
        float sr2 = (s0 + s1) + (s2 + s3);
        sr2 += __shfl_xor(sr2, 1, 64);

        float dmin = 3.4e38f;
        int best = 0;
        for (int pass = 0; pass < 4; ++pass) {
            __syncthreads();
            const float* src = cb + ((size_t)s * 512 + pass * 128) * 64;
            for (int i2 = tid; i2 < 128 * 64 / 4; i2 += 128)
                ((float4*)scb)[i2] = ((const float4*)src)[i2];
            ssc[tid] = nrm[(size_t)s * 512 + pass * 128 + tid];
            __syncthreads();
#pragma unroll 2
            for (int kk = 0; kk < 128; ++kk) {
                const float4* cp = (const float4*)&scb[kk * 64 + h * 32];
                float d0 = 0.f, d1 = 0.f, d2 = 0.f, d3 = 0.f;
#pragma unroll
                for (int i = 0; i < 8; ++i) {
                    float4 c = cp[i];
                    d0 = fmaf(r[4 * i + 0], c.x, d0);
                    d1 = fmaf(r[4 * i + 1], c.y, d1);
                    d2 = fmaf(r[4 * i + 2], c.z, d2);
                    d3 = fmaf(r[4 * i + 3], c.w, d3);
                }
                float dot = (d0 + d1) + (d2 + d3);
                dot += __shfl_xor(dot, 1, 64);
                const float d = fmaf(-2.f, dot, sr2) + ssc[kk];
                if (d < dmin) { dmin = d; best = pass * 128 + kk; }
            }
        }
        float lv = (h == 0) ? dmin : 0.f;
#pragma unroll
        for (int off = 32; off; off >>= 1) lv += __shfl_down(lv, off, 64);
        if ((tid & 63) == 0) atomicAdd(&loss_acc[s], lv);

        if (h == 0) idx_out[(size_t)t * 4 + s] = (float)best;

        const float4* cbest = (const float4*)(cb + ((size_t)s * 512 + best) * 64 + h * 32);
#pragma unroll
        for (int i = 0; i < 8; ++i) {
            float4 c = cbest[i];
            r[4 * i + 0] -= c.x; r[4 * i + 1] -= c.y;
            r[4 * i + 2] -= c.z; r[4 * i + 3] -= c.w;
        }
    }
    const int n = t >> 12, pix = t & 4095;
    float* qp = q + (size_t)n * 64 * 4096 + pix;
#pragma unroll
    for (int i = 0; i < 32; ++i)
        qp[(size_t)(h * 32 + i) * 4096] = zr[i] - r[i];
}

__global__ void init_k(float* loss_acc) {
    if (threadIdx.x < 4) loss_acc[threadIdx.x] = 0.f;
}
__global__ void fin_k(const float* __restrict__ loss_acc, float* __restrict__ out_loss) {
    if (threadIdx.x < 4)
        out_loss[threadIdx.x] = loss_acc[threadIdx.x] * (0.25f / 4194304.f); // BETA/(N*D)
}

// ---------------------------------------------------------------------------
extern "C" void kernel_launch(void* const* d_in, const int* in_sizes, int n_in,
                              void* d_out, int out_size, void* d_ws, size_t ws_size,
                              hipStream_t stream)
{
    const float* x    = (const float*)d_in[0];
    const float* e1w  = (const float*)d_in[1];  const float* e1b = (const float*)d_in[2];
    const float* e2w  = (const float*)d_in[3];  const float* e2b = (const float*)d_in[4];
    const float* e3w  = (const float*)d_in[5];  const float* e3b = (const float*)d_in[6];
    const float* r1aw = (const float*)d_in[7];  const float* r1bw = (const float*)d_in[8];
    const float* r2aw = (const float*)d_in[9];  const float* r2bw = (const float*)d_in[10];
    const float* e4w  = (const float*)d_in[11]; const float* e4b = (const float*)d_in[12];
    const float* cbs  = (const float*)d_in[13];
    const float* d1w  = (const float*)d_in[14]; const float* d1b = (const float*)d_in[15];
    const float* dr1aw= (const float*)d_in[16]; const float* dr1bw = (const float*)d_in[17];
    const float* dr2aw= (const float*)d_in[18]; const float* dr2bw = (const float*)d_in[19];
    const float* dt1w = (const float*)d_in[20]; const float* dt1b = (const float*)d_in[21];
    const float* dt2w = (const float*)d_in[22]; const float* dt2b = (const float*)d_in[23];

    float* out = (float*)d_out;
    float* ws  = (float*)d_ws;

    float* BIG = ws;                    // 16.78M floats (e1 out / dt1 out)
    float* P2  = BIG;
    float* P3  = BIG + 8388608;
    float* P1  = ws + 16777216;
    float* Z   = ws + 25165824;
    float* Q   = ws + 29360128;
    float* LACC= ws + 33554432;         // 4 floats
    float* NRM = ws + 33554448;         // 2048 floats

    float* out_recons = out;                    // 16*4*256*256 = 4194304
    float* out_idx    = out + 4194304;          // 16*64*64*4   = 262144
    float* out_loss   = out + 4194304 + 262144; // 4

    init_k<<<1, 64, 0, stream>>>(LACC);
    norm_k<<<8, 256, 0, stream>>>(cbs, NRM);

    // ---- encoder ----
    conv_k<4, 64, 4, 2, 1, 256, 256, 128, 128, 4, 1, 2, true>
        <<<dim3(64, 4, 16), 256, 0, stream>>>(x, e1w, e1b, BIG);
    conv_k<64, 128, 4, 2, 1, 128, 128, 64, 64, 16, 2, 2, true>
        <<<dim3(8, 8, 16), 256, 0, stream>>>(BIG, e2w, e2b, P1);
    conv_k<128, 128, 3, 1, 1, 64, 64, 64, 64, 16, 4, 2, true>
        <<<dim3(4, 8, 16), 256, 0, stream>>>(P1, e3w, e3b, P2);
    conv_k<128, 128, 3, 1, 1, 64, 64, 64, 64, 16, 4, 1, false>
        <<<dim3(4, 8, 16), 256, 0, stream>>>(P2, r1aw, nullptr, P3);
    conv1x1_k<128, 128, 4, 0, false, false, true, false>
        <<<dim3(4, 8, 16), 256, 0, stream>>>(P3, r1bw, nullptr, P2, P1);
    conv_k<128, 128, 3, 1, 1, 64, 64, 64, 64, 16, 4, 1, false>
        <<<dim3(4, 8, 16), 256, 0, stream>>>(P1, r2aw, nullptr, P3);
    conv1x1_k<128, 128, 4, 0, false, false, true, false>
        <<<dim3(4, 8, 16), 256, 0, stream>>>(P3, r2bw, nullptr, P1, P2);
    conv1x1_k<128, 64, 2, 2, true, true, false, true>
        <<<dim3(8, 4, 16), 256, 0, stream>>>(P2, e4w, e4b, nullptr, Z);

    // ---- residual VQ ----
    rvq_k<<<1024, 128, 0, stream>>>(Z, cbs, NRM, Q, out_idx, LACC);
    fin_k<<<1, 64, 0, stream>>>(LACC, out_loss);

    // ---- decoder ----
    conv_k<64, 128, 3, 1, 1, 64, 64, 64, 64, 16, 4, 2, true>
        <<<dim3(4, 8, 16), 256, 0, stream>>>(Q, d1w, d1b, P1);
    conv_k<128, 128, 3, 1, 1, 64, 64, 64, 64, 16, 4, 1, false>
        <<<dim3(4, 8, 16), 256, 0, stream>>>(P1, dr1aw, nullptr, P2);
    conv1x1_k<128, 128, 4, 0, false, false, true, false>
        <<<dim3(4, 8, 16), 256, 0, stream>>>(P2, dr1bw, nullptr, P1, P3);
    conv_k<128, 128, 3, 1, 1, 64, 64, 64, 64, 16, 4, 1, false>
        <<<dim3(4, 8, 16), 256, 0, stream>>>(P3, dr2aw, nullptr, P2);
    conv1x1_k<128, 128, 4, 0, false, false, true, false>
        <<<dim3(4, 8, 16), 256, 0, stream>>>(P2, dr2bw, nullptr, P3, P1);
    convt_k<128, 64, 16, 64, 8, 2, true>
        <<<dim3(16, 4, 16), 256, 0, stream>>>(P1, dt1w, dt1b, BIG);
    convt_k<64, 4, 4, 128, 16, 1, false>
        <<<dim3(64, 1, 16), 256, 0, stream>>>(BIG, dt2w, dt2b, out_recons);
}